// Round 5
// baseline (146.624 us; speedup 1.0000x reference)
//
#include <hip/hip_runtime.h>
#include <hip/hip_bf16.h>
#include <stdint.h>

#define T_TOKENS 8192
#define D_DIM 1024
#define H_DIM 2048
#define N_EXPERTS 8

typedef __attribute__((ext_vector_type(8))) short bf16x8;
typedef __attribute__((ext_vector_type(4))) float f32x4;

typedef __attribute__((address_space(1))) const void* gptr_t;
typedef __attribute__((address_space(3))) void* lptr_t;

__device__ __forceinline__ unsigned short f2bf(float f) {
  union { float f; unsigned int u; } x; x.f = f;
  unsigned int r = x.u + 0x7FFFu + ((x.u >> 16) & 1u);
  return (unsigned short)(r >> 16);
}
__device__ __forceinline__ float bf2f(unsigned short b) {
  union { unsigned int u; float f; } x; x.u = ((unsigned int)b) << 16;
  return x.f;
}

__device__ __forceinline__ void gload16(const void* g, void* l) {
  __builtin_amdgcn_global_load_lds((gptr_t)g, (lptr_t)l, 16, 0, 0);
}

// Sync discipline (rule #18: sched_barrier after inline-asm waits / raw barriers)
#define SBAR()  do { __builtin_amdgcn_s_barrier(); __builtin_amdgcn_sched_barrier(0); } while (0)
#define LGKM0() do { asm volatile("s_waitcnt lgkmcnt(0)" ::: "memory"); __builtin_amdgcn_sched_barrier(0); } while (0)
#define VMW(n)  do { __builtin_amdgcn_sched_barrier(0); asm volatile("s_waitcnt vmcnt(" #n ")" ::: "memory"); } while (0)

// ---------------------------------------------------------------------------
// fp32 -> bf16 conversion — EXACT round-1 structure (measured 36us for all
// three arrays): one pure-stream kernel per array, 2048 blocks, grid-stride,
// float4 loads (16B/lane) + ushort4 stores (8B/lane), 4-8 iters/thread.
// R2's branch-fused (72us) and R4's single-shot region (64-70us) variants
// were both ~2x slower despite zero VALU/conflict pressure.
// ---------------------------------------------------------------------------
__global__ void cvt_f32_bf16_kernel(const float* __restrict__ in,
                                    unsigned short* __restrict__ out, int n) {
  int tid = blockIdx.x * blockDim.x + threadIdx.x;
  int stride = gridDim.x * blockDim.x;
  for (int i = tid * 4; i < n; i += stride * 4) {
    const float4 v = *reinterpret_cast<const float4*>(in + i);
    ushort4 o;
    o.x = f2bf(v.x); o.y = f2bf(v.y); o.z = f2bf(v.z); o.w = f2bf(v.w);
    *reinterpret_cast<ushort4*>(out + i) = o;
  }
}

// ---------------------------------------------------------------------------
// Grouped GEMM (measured-fast structure, used for BOTH matmuls):
// C[M,N] = A[M,K] @ B[e][N,K]^T over expert row segments.
// BM=256 BN=128 BK=64. 8 waves 4Mx2N (per-wave 64x64, acc[4][4]).
// 2 phases per K-tile (K-half each), counted vmcnt(6) every phase (2 K-halves
// in flight), one s_barrier per phase, setprio around the 16-MFMA cluster.
// LDS: 4 K-half slots per operand: lA 4x[256][32] (64KB) + lB 4x[128][32]
// (32KB) = 96KB -> 1 block/CU. XOR-swizzled granules (conflict-free, rule #21:
// pre-swizzled GLOBAL source + linear LDS dest + swizzled read).
// FUSE=true: O=bf16(relu(bf16(acc))^2) -> OB. FUSE=false: O=f32(bf16(acc)) -> OF.
// ---------------------------------------------------------------------------
template <int K, int N, bool FUSE>
__global__ __launch_bounds__(512, 2)
void ggemm(const unsigned short* __restrict__ A,
           const unsigned short* __restrict__ B,
           const int* __restrict__ counts,
           unsigned short* __restrict__ OB,
           float* __restrict__ OF) {
  constexpr int NT = K / 64;
  constexpr int NCB = N / 128;  // column panels
  __shared__ short lA[4 * 8192];
  __shared__ short lB[4 * 4096];

  const int tid = threadIdx.x;
  const int wid = tid >> 6, lane = tid & 63;
  const int wr = wid >> 1, wc = wid & 1;
  const int bid = blockIdx.x;
  const int cb = bid % NCB, rb = bid / NCB;  // same-cb blocks share an XCD (NCB%8==0)
  const int r0 = rb * 256, c0 = cb * 128;

  int csum[N_EXPERTS + 1];
  csum[0] = 0;
  for (int e = 0; e < N_EXPERTS; ++e) csum[e + 1] = csum[e] + counts[e];
  int eLo = 0;
  while (eLo < N_EXPERTS - 1 && csum[eLo + 1] <= r0) ++eLo;
  int eHi = eLo;
  while (eHi < N_EXPERTS - 1 && csum[eHi + 1] < r0 + 256) ++eHi;

  // staging: lane -> row (lane>>2), XOR-swizzled 16B granule (rule #21: swizzle
  // the GLOBAL source, LDS dest linear)
  const int srow = lane >> 2;
  const int scol = ((lane & 3) ^ ((lane >> 3) & 3)) * 8;
  const size_t aBase = (size_t)(r0 + wid * 16 + srow) * K + scol;
  const size_t bBase0 = (size_t)(c0 + wid * 16 + srow) * K + scol;
  const int ldsW = wid * 512;
  const int l15 = lane & 15;
  const int l4 = ((lane >> 4) ^ ((lane >> 1) & 3)) * 8;  // swizzled read granule

  for (int e = eLo; e <= eHi; ++e) {
    const unsigned short* Be = B + (size_t)e * N * K;
    f32x4 acc[4][4];
#pragma unroll
    for (int mi = 0; mi < 4; ++mi)
#pragma unroll
      for (int ni = 0; ni < 4; ++ni) acc[mi][ni] = (f32x4){0.f, 0.f, 0.f, 0.f};

#define STAGE_A(t, h) do { const int s_ = (((t) & 1) << 1) | (h); \
    gload16(A + aBase + (size_t)(t) * 64 + (h) * 32,                 &lA[s_ * 8192 + ldsW]); \
    gload16(A + aBase + (size_t)128 * K + (size_t)(t) * 64 + (h) * 32, &lA[s_ * 8192 + ldsW + 4096]); } while (0)
#define STAGE_B(t, h) do { const int s_ = (((t) & 1) << 1) | (h); \
    gload16(Be + bBase0 + (size_t)(t) * 64 + (h) * 32, &lB[s_ * 4096 + ldsW]); } while (0)
#define G_RD(SLOT) do { \
    _Pragma("unroll") for (int m_ = 0; m_ < 4; ++m_) \
      fa[m_] = *(const bf16x8*)&lA[(SLOT) * 8192 + (wr * 64 + m_ * 16 + l15) * 32 + l4]; \
    _Pragma("unroll") for (int n_ = 0; n_ < 4; ++n_) \
      fb[n_] = *(const bf16x8*)&lB[(SLOT) * 4096 + (wc * 64 + n_ * 16 + l15) * 32 + l4]; \
  } while (0)
#define G_MM() do { \
    __builtin_amdgcn_s_setprio(1); \
    _Pragma("unroll") for (int m_ = 0; m_ < 4; ++m_) \
      _Pragma("unroll") for (int n_ = 0; n_ < 4; ++n_) \
        acc[m_][n_] = __builtin_amdgcn_mfma_f32_16x16x32_bf16(fa[m_], fb[n_], acc[m_][n_], 0, 0, 0); \
    __builtin_amdgcn_s_setprio(0); \
  } while (0)

    STAGE_A(0, 0); STAGE_B(0, 0); STAGE_A(0, 1); STAGE_B(0, 1);
    STAGE_A(1, 0); STAGE_B(1, 0);
    VMW(6); SBAR();

#pragma unroll 1
    for (int t = 0; t < NT - 2; ++t) {
      const int k0 = ((t & 1) << 1), k1 = k0 | 1;
      { bf16x8 fa[4], fb[4]; G_RD(k0); STAGE_A(t + 1, 1); STAGE_B(t + 1, 1); VMW(6); LGKM0(); G_MM(); SBAR(); }
      { bf16x8 fa[4], fb[4]; G_RD(k1); STAGE_A(t + 2, 0); STAGE_B(t + 2, 0); VMW(6); LGKM0(); G_MM(); SBAR(); }
    }
    {  // t = NT-2
      const int k0 = (((NT - 2) & 1) << 1), k1 = k0 | 1;
      { bf16x8 fa[4], fb[4]; G_RD(k0); STAGE_A(NT - 1, 1); STAGE_B(NT - 1, 1); VMW(6); LGKM0(); G_MM(); SBAR(); }
      { bf16x8 fa[4], fb[4]; G_RD(k1);                                        VMW(3); LGKM0(); G_MM(); SBAR(); }
    }
    {  // t = NT-1
      const int k0 = (((NT - 1) & 1) << 1), k1 = k0 | 1;
      { bf16x8 fa[4], fb[4]; G_RD(k0);                                        VMW(0); LGKM0(); G_MM(); SBAR(); }
      { bf16x8 fa[4], fb[4]; G_RD(k1);                                                LGKM0(); G_MM(); SBAR(); }
    }

    // epilogue: C/D layout col=lane&15, row=(lane>>4)*4+reg
    const int segLo = csum[e], segHi = csum[e + 1];
#pragma unroll
    for (int mi = 0; mi < 4; ++mi) {
      const int rowb = r0 + wr * 64 + mi * 16 + ((lane >> 4) << 2);
#pragma unroll
      for (int ni = 0; ni < 4; ++ni) {
        const int col = c0 + wc * 64 + ni * 16 + l15;
#pragma unroll
        for (int r = 0; r < 4; ++r) {
          const int gr = rowb + r;
          if (gr >= segLo && gr < segHi) {
            if (FUSE) {
              float h = bf2f(f2bf(acc[mi][ni][r]));
              h = h > 0.f ? h : 0.f;
              OB[(size_t)gr * N + col] = f2bf(h * h);
            } else {
              OF[(size_t)gr * N + col] = bf2f(f2bf(acc[mi][ni][r]));
            }
          }
        }
      }
    }
#undef STAGE_A
#undef STAGE_B
#undef G_RD
#undef G_MM
  }
}

extern "C" void kernel_launch(void* const* d_in, const int* in_sizes, int n_in,
                              void* d_out, int out_size, void* d_ws, size_t ws_size,
                              hipStream_t stream) {
  const float* x = (const float*)d_in[0];
  const float* w_up = (const float*)d_in[1];
  const float* w_down = (const float*)d_in[2];
  const int* counts = (const int*)d_in[3];
  float* out = (float*)d_out;

  char* ws = (char*)d_ws;
  unsigned short* xb  = (unsigned short*)(ws);
  unsigned short* wub = (unsigned short*)(ws + (size_t)16 * 1024 * 1024);
  unsigned short* wdb = (unsigned short*)(ws + (size_t)48 * 1024 * 1024);
  unsigned short* hsq = (unsigned short*)(ws + (size_t)80 * 1024 * 1024);

  cvt_f32_bf16_kernel<<<2048, 256, 0, stream>>>(x, xb, T_TOKENS * D_DIM);
  cvt_f32_bf16_kernel<<<2048, 256, 0, stream>>>(w_up, wub, N_EXPERTS * H_DIM * D_DIM);
  cvt_f32_bf16_kernel<<<2048, 256, 0, stream>>>(w_down, wdb, N_EXPERTS * D_DIM * H_DIM);

  // GEMM1: hsq = bf16(relu(bf16(x @ w_up^T))^2)  (T,H); grid 32 rb x 16 cb
  ggemm<D_DIM, H_DIM, true>
      <<<(T_TOKENS / 256) * (H_DIM / 128), 512, 0, stream>>>(xb, wub, counts, hsq, nullptr);
  // GEMM2: out = f32(bf16(hsq @ w_down^T))  (T,D); grid 32 rb x 8 cb
  ggemm<H_DIM, D_DIM, false>
      <<<(T_TOKENS / 256) * (D_DIM / 128), 512, 0, stream>>>(hsq, wdb, counts, nullptr, out);
}